// Round 1
// baseline (2269.889 us; speedup 1.0000x reference)
//
#include <hip/hip_runtime.h>
#include <math.h>

namespace {
constexpr int kD  = 512;
constexpr int kB  = 128;
constexpr int kKP = 2048;       // K + NPOS
constexpr int kNF = 16084;
constexpr int kNP = 604731;
constexpr float kTinv = 1.0f / 0.07f;
}

// d_out regions start at out+1 (4-byte aligned only) -> reduced-alignment vec4
typedef float f4u __attribute__((ext_vector_type(4), aligned(4)));
typedef float f4  __attribute__((ext_vector_type(4), aligned(16)));

__global__ __launch_bounds__(256) void copy_mem_kernel(const f4* __restrict__ src,
                                                       f4u* __restrict__ dst, int n4) {
    int i = blockIdx.x * blockDim.x + threadIdx.x;
    int stride = gridDim.x * blockDim.x;
    for (; i < n4; i += stride) dst[i] = src[i];
}

// One wave per k-row: load 2KB mem row coalesced, dot with v1[b] and v2[b].
__global__ __launch_bounds__(256) void logits_kernel(
        const float* __restrict__ v1, const float* __restrict__ v2,
        const int* __restrict__ idx1, const int* __restrict__ idx2,
        const float* __restrict__ mem1, const float* __restrict__ mem2,
        float* __restrict__ sbuf) {
    int b = blockIdx.x >> 6;        // 128 b values
    int chunk = blockIdx.x & 63;    // 64 chunks of 64 k-values
    int wave = threadIdx.x >> 6;    // 4 waves/block
    int lane = threadIdx.x & 63;

    const f4* v1p = (const f4*)(v1 + b * kD);
    const f4* v2p = (const f4*)(v2 + b * kD);
    f4 va0 = v1p[2 * lane], va1 = v1p[2 * lane + 1];
    f4 vb0 = v2p[2 * lane], vb1 = v2p[2 * lane + 1];

    int k0 = chunk * 64 + wave * 16;        // 16 k per wave
    bool first = (k0 < kKP);                // chunks never cross the 2048 boundary
    const int* idx = first ? (idx1 + b * kKP + k0) : (idx2 + b * kKP + (k0 - kKP));
    const float* mem = first ? mem1 : mem2;

    for (int i = 0; i < 16; ++i) {
        int row = idx[i];
        const f4* wp = (const f4*)(mem + (size_t)row * kD);
        f4 w0 = wp[2 * lane], w1 = wp[2 * lane + 1];
        float d1 = w0[0]*va0[0] + w0[1]*va0[1] + w0[2]*va0[2] + w0[3]*va0[3]
                 + w1[0]*va1[0] + w1[1]*va1[1] + w1[2]*va1[2] + w1[3]*va1[3];
        float d2 = w0[0]*vb0[0] + w0[1]*vb0[1] + w0[2]*vb0[2] + w0[3]*vb0[3]
                 + w1[0]*vb1[0] + w1[1]*vb1[1] + w1[2]*vb1[2] + w1[3]*vb1[3];
        for (int off = 32; off; off >>= 1) {
            d1 += __shfl_xor(d1, off);
            d2 += __shfl_xor(d2, off);
        }
        if (lane == 0) {
            int k = k0 + i;
            sbuf[(size_t)b * 4096 + k]         = d1 * kTinv;   // row t=0
            sbuf[(size_t)(kB + b) * 4096 + k]  = d2 * kTinv;   // row t=1
        }
    }
}

// One block per logits row r (256 rows x 4096 cols): max, logsumexp, pos log-probs.
__global__ __launch_bounds__(256) void row_softmax_kernel(const float* __restrict__ sbuf,
                                                          float* __restrict__ rowval) {
    int r = blockIdx.x;
    const float* row = sbuf + (size_t)r * 4096;
    int t = threadIdx.x;

    float mx = -INFINITY;
    for (int i = t; i < 4096; i += 256) mx = fmaxf(mx, row[i]);
    for (int off = 32; off; off >>= 1) mx = fmaxf(mx, __shfl_xor(mx, off));
    __shared__ float smax[4];
    if ((t & 63) == 0) smax[t >> 6] = mx;
    __syncthreads();
    mx = fmaxf(fmaxf(smax[0], smax[1]), fmaxf(smax[2], smax[3]));

    float se = 0.0f;
    for (int i = t; i < 4096; i += 256) se += expf(row[i] - mx);
    for (int off = 32; off; off >>= 1) se += __shfl_xor(se, off);
    __shared__ float ssum[4];
    if ((t & 63) == 0) ssum[t >> 6] = se;
    __syncthreads();

    if (t == 0) {
        float lse = logf(ssum[0] + ssum[1] + ssum[2] + ssum[3]);
        // pos columns after repeat: 0 and kKP
        float lp = 0.5f * ((row[0] - mx - lse) + (row[kKP] - mx - lse));
        rowval[r] = lp;
    }
}

__global__ __launch_bounds__(256) void loss_kernel(const float* __restrict__ rowval,
                                                   float* __restrict__ out) {
    int t = threadIdx.x;
    float v = rowval[t];
    for (int off = 32; off; off >>= 1) v += __shfl_xor(v, off);
    __shared__ float s[4];
    if ((t & 63) == 0) s[t >> 6] = v;
    __syncthreads();
    if (t == 0) out[0] = -(s[0] + s[1] + s[2] + s[3]) * (1.0f / 256.0f);
}

// One block (128 thr) per batch row: p = 0.5*mem[y]+0.5*v, L2-normalize, scatter.
// Duplicate indices: last occurrence wins (numpy a[y]=p semantics).
__global__ __launch_bounds__(128) void momentum_kernel(const float* __restrict__ mem,
        const float* __restrict__ v, const int* __restrict__ y,
        float* __restrict__ out_mem, int nb) {
    int b = blockIdx.x;
    int yb = y[b];
    for (int b2 = b + 1; b2 < nb; ++b2)
        if (y[b2] == yb) return;        // a later write would overwrite ours

    int t = threadIdx.x;
    const f4* mp = (const f4*)(mem + (size_t)yb * kD);
    const f4* vp = (const f4*)(v + (size_t)b * kD);
    f4 m = mp[t], vv = vp[t];
    f4 p;
    p[0] = 0.5f * m[0] + 0.5f * vv[0];
    p[1] = 0.5f * m[1] + 0.5f * vv[1];
    p[2] = 0.5f * m[2] + 0.5f * vv[2];
    p[3] = 0.5f * m[3] + 0.5f * vv[3];

    float ss = p[0]*p[0] + p[1]*p[1] + p[2]*p[2] + p[3]*p[3];
    for (int off = 32; off; off >>= 1) ss += __shfl_xor(ss, off);
    __shared__ float sred[2];
    if ((t & 63) == 0) sred[t >> 6] = ss;
    __syncthreads();
    float inv = 1.0f / sqrtf(sred[0] + sred[1]);

    f4u o;
    o[0] = p[0] * inv; o[1] = p[1] * inv; o[2] = p[2] * inv; o[3] = p[3] * inv;
    ((f4u*)(out_mem + (size_t)yb * kD))[t] = o;
}

extern "C" void kernel_launch(void* const* d_in, const int* in_sizes, int n_in,
                              void* d_out, int out_size, void* d_ws, size_t ws_size,
                              hipStream_t stream) {
    const float* v1   = (const float*)d_in[0];
    const int*   y1   = (const int*)d_in[1];
    const float* v2   = (const float*)d_in[2];
    const int*   y2   = (const int*)d_in[3];
    const int*   idx1 = (const int*)d_in[4];
    const int*   idx2 = (const int*)d_in[5];
    const float* mem1 = (const float*)d_in[6];
    const float* mem2 = (const float*)d_in[7];

    float* out    = (float*)d_out;
    float* out_m1 = out + 1;
    float* out_m2 = out + 1 + (size_t)kNF * kD;

    float* sbuf   = (float*)d_ws;                   // 256*4096 floats = 4 MB
    float* rowval = sbuf + (size_t)256 * 4096;      // 256 floats

    int n4_1 = kNF * kD / 4;                        // 2,058,752
    int n4_2 = (int)((size_t)kNP * kD / 4);         // 77,405,568

    hipLaunchKernelGGL(copy_mem_kernel, dim3(1024), dim3(256), 0, stream,
                       (const f4*)mem1, (f4u*)out_m1, n4_1);
    hipLaunchKernelGGL(copy_mem_kernel, dim3(8192), dim3(256), 0, stream,
                       (const f4*)mem2, (f4u*)out_m2, n4_2);
    hipLaunchKernelGGL(logits_kernel, dim3(kB * 64), dim3(256), 0, stream,
                       v1, v2, idx1, idx2, mem1, mem2, sbuf);
    hipLaunchKernelGGL(row_softmax_kernel, dim3(256), dim3(256), 0, stream, sbuf, rowval);
    hipLaunchKernelGGL(loss_kernel, dim3(1), dim3(256), 0, stream, rowval, out);
    hipLaunchKernelGGL(momentum_kernel, dim3(kB), dim3(128), 0, stream,
                       mem1, v1, y1, out_m1, kB);
    hipLaunchKernelGGL(momentum_kernel, dim3(kB), dim3(128), 0, stream,
                       mem2, v2, y2, out_m2, kB);
}